// Round 4
// baseline (3640.464 us; speedup 1.0000x reference)
//
#include <hip/hip_runtime.h>

// ---------------------------------------------------------------------------
// BBCU binary SR network, round 15.
// R14 failed (absmax 0.855): prime suspect is cgrp::grid_group::sync() under
// the harness's graph capture (cooperative launch captured as a plain node ->
// broken grid barrier -> cross-block races). NHWC conv_last path re-audited
// and kept.
// This round:
//   1. Fused head+32-body persistent kernel with a HAND-ROLLED two-level
//      sense-reversing grid barrier (agent-scope seq_cst atomics + fences,
//      state zeroed via hipMemsetAsync; regular launch, no cooperative API).
//      1024 blocks @ __launch_bounds__(256,4): VGPR<=128, LDS 5.9KB ->
//      4 blocks/CU co-resident guaranteed.
//   2. Residual features live in REGISTERS across all 32 layers (16 f32 per
//      thread, static indexing); per layer only u16 bit-packs are stored and
//      9 halo u64s loaded -> the 32x33MB f32 ping-pong traffic vanishes.
//   3. hr writes V in NHWC with leaky pre-applied; conv_last reads float4
//      pixel vectors (16x16 tiles).
// All arithmetic op-for-op identical to the R13 passing kernel.
// ws: A[0,16) PV[16,80) U[80,144) bitsA/B[144,145) bits256[145,146)
//     bits512[146,148) wbits[149,..) scales[150,..) bar[151,..)
// ---------------------------------------------------------------------------

typedef unsigned long long u64;
typedef unsigned int u32;
typedef unsigned short u16;

#define NBLK 1024

__device__ inline float fadd(float a, float b) { return __fadd_rn(a, b); }
__device__ inline float fmul(float a, float b) { return __fmul_rn(a, b); }

// numpy pairwise sum of |p[0..n)| (exact numpy algorithm, f32) — for scale
__device__ float pw_abs_sum(const float* p, int n) {
  if (n <= 8) {
    float s = fabsf(p[0]);
    for (int i = 1; i < n; i++) s = fadd(s, fabsf(p[i]));
    return s;
  }
  if (n <= 128) {
    float r[8];
#pragma unroll
    for (int q = 0; q < 8; q++) r[q] = fabsf(p[q]);
    int i;
    for (i = 8; i + 8 <= n; i += 8)
#pragma unroll
      for (int q = 0; q < 8; q++) r[q] = fadd(r[q], fabsf(p[i + q]));
    float res = fadd(fadd(fadd(r[0], r[1]), fadd(r[2], r[3])),
                     fadd(fadd(r[4], r[5]), fadd(r[6], r[7])));
    for (; i < n; i++) res = fadd(res, fabsf(p[i]));
    return res;
  }
  int n2 = (n / 2) & ~7;
  return fadd(pw_abs_sum(p, n2), pw_abs_sum(p + n2, n - n2));
}

// --- diagnostic ------------------------------------------------------------
__global__ __launch_bounds__(256) void diag_kernel(float* __restrict__ out,
                                                   int n, float tag) {
  int idx = blockIdx.x * 256 + threadIdx.x;
  if (idx < n) out[idx] = (idx == 0) ? tag : 0.f;
}

// --- weight prep: scale (numpy pairwise mean|w|) + 9 x u64 sign bits -------
__global__ __launch_bounds__(64) void binw_pack_kernel(
    const float* __restrict__ w, u64* __restrict__ wbits,
    float* __restrict__ scale, int nch) {
  int ch = blockIdx.x * 64 + threadIdx.x;
  if (ch >= nch) return;
  const float* wc = w + (size_t)ch * 576;
  float S = pw_abs_sum(wc, 576);
  scale[ch] = __fdiv_rn(S, 576.0f);
  u64 b[9] = {0, 0, 0, 0, 0, 0, 0, 0, 0};
  for (int ci = 0; ci < 64; ci++) {
#pragma unroll
    for (int tap = 0; tap < 9; tap++)
      b[tap] |= (u64)(wc[ci * 9 + tap] > 0.0f) << ci;
  }
#pragma unroll
  for (int tap = 0; tap < 9; tap++) wbits[(size_t)ch * 9 + tap] = b[tap];
}

// --- hand-rolled grid barrier (two-level, sense-reversing) -----------------
// bar layout (u32): [0..511] 32 leaf counters @ stride 16 (64B lines),
//                   [512] root, [520] generation.
__device__ inline void grid_barrier(u32* bar, int blk) {
  __syncthreads();
  if (threadIdx.x == 0) {
    u32* leaf = bar + (blk & 31) * 16;
    u32* root = bar + 512;
    u32* gen = bar + 520;
    u32 g = __hip_atomic_load(gen, __ATOMIC_SEQ_CST, __HIP_MEMORY_SCOPE_AGENT);
    __threadfence();  // release my writes (bits) to agent scope
    u32 lo = __hip_atomic_fetch_add(leaf, 1u, __ATOMIC_SEQ_CST,
                                    __HIP_MEMORY_SCOPE_AGENT);
    if (lo == 31u) {
      __hip_atomic_store(leaf, 0u, __ATOMIC_SEQ_CST, __HIP_MEMORY_SCOPE_AGENT);
      u32 ro = __hip_atomic_fetch_add(root, 1u, __ATOMIC_SEQ_CST,
                                      __HIP_MEMORY_SCOPE_AGENT);
      if (ro == 31u) {
        __hip_atomic_store(root, 0u, __ATOMIC_SEQ_CST,
                           __HIP_MEMORY_SCOPE_AGENT);
        __hip_atomic_store(gen, g + 1u, __ATOMIC_SEQ_CST,
                           __HIP_MEMORY_SCOPE_AGENT);
      }
    }
    while (__hip_atomic_load(gen, __ATOMIC_RELAXED,
                             __HIP_MEMORY_SCOPE_AGENT) == g)
      __builtin_amdgcn_s_sleep(2);
    __threadfence();  // acquire others' writes
  }
  __syncthreads();
}

// --- fused head + 32 body layers (persistent, regular launch) --------------
// Grid MUST be exactly NBLK=1024 blocks x 256 thr (4 blocks/CU resident:
// launch_bounds forces VGPR<=128; LDS 5.9KB).
__global__ __launch_bounds__(256, 4) void fused_body_kernel(
    const float* __restrict__ x,          // (4,3,128,128)
    const float* __restrict__ cfw, const float* __restrict__ cfb,
    const float* __restrict__ body_move,  // (32,64)
    const float* __restrict__ body_a, const float* __restrict__ body_b1,
    const float* __restrict__ body_b2,
    const float* __restrict__ up1_move,   // (64)
    float* __restrict__ A,                // (4,64,128,128) final body out
    u64* __restrict__ bitsA, u64* __restrict__ bitsB,  // (4,16384) each
    const u64* __restrict__ wbits,        // (2048,9)
    const float* __restrict__ scales,     // (2048)
    u32* __restrict__ bar) {
  __shared__ u64 s_w[576];
  __shared__ float s_sc[64], s_a[64], s_b1[64], s_b2[64], s_mv[64];

  int t = threadIdx.x;
  int blk = blockIdx.x;
  int bx = blk & 7, by = (blk >> 3) & 31, n = blk >> 8;
  int px = bx * 16 + (t & 15);
  int py = by * 4 + ((t >> 4) & 3);
  int cg = t >> 6;                        // wave-uniform co-group
  int pix = py * 128 + px;

  float res[16];                          // residual features, in registers

  // ---- Phase A: conv_first for own pixel, channels [cg*16, cg*16+16) -----
  // Zero-filled OOB taps: fmaf(0,w,acc)==acc bit-exactly (acc stays +0).
  {
    const float* xn = x + (size_t)n * 49152;
    float xv[27];
#pragma unroll
    for (int ky = 0; ky < 3; ky++) {
      int yy = py + ky - 1;
#pragma unroll
      for (int kx = 0; kx < 3; kx++) {
        int xx = px + kx - 1;
        bool ok = (yy >= 0 && yy < 128 && xx >= 0 && xx < 128);
#pragma unroll
        for (int ci = 0; ci < 3; ci++)
          xv[(ky * 3 + kx) * 3 + ci] =
              ok ? xn[ci * 16384 + yy * 128 + xx] : 0.0f;
      }
    }
    u32 pk = 0;
#pragma unroll
    for (int q = 0; q < 16; q++) {
      int co = cg * 16 + q;
      const float* wp = cfw + co * 27;
      float acc = 0.f;
#pragma unroll
      for (int ky = 0; ky < 3; ky++)
#pragma unroll
        for (int kx = 0; kx < 3; kx++)
#pragma unroll
          for (int ci = 0; ci < 3; ci++)
            acc = fmaf(xv[(ky * 3 + kx) * 3 + ci],
                       wp[ci * 9 + ky * 3 + kx], acc);
      float wb = fadd(acc, cfb[co]);
      float r = wb >= 0.f ? wb : fmul(0.1f, wb);
      res[q] = r;
      pk |= (u32)(fadd(r, body_move[co]) > 0.0f) << q;
    }
    ((u16*)(bitsA + (size_t)n * 16384))[pix * 4 + cg] = (u16)pk;
  }
  grid_barrier(bar, blk);

  // ---- Phase B: 32 body layers; only bit-packs touch global --------------
  u64* bin = bitsA + (size_t)n * 16384;
  u64* bout = bitsB + (size_t)n * 16384;
  for (int u = 0; u < 32; u++) {
    const u64* wl = wbits + (size_t)u * 576;
    for (int i = t; i < 576; i += 256) s_w[i] = wl[i];
    if (t < 64) {
      s_sc[t] = scales[u * 64 + t];
      s_a[t] = body_a[u * 64 + t];
      s_b1[t] = body_b1[u * 64 + t];
      s_b2[t] = body_b2[u * 64 + t];
      s_mv[t] = (u < 31) ? body_move[(u + 1) * 64 + t] : up1_move[t];
    }
    __syncthreads();

    u64 nb[9];
    int vf = 0, nvalid = 0;
#pragma unroll
    for (int ky = 0; ky < 3; ky++)
#pragma unroll
      for (int kx = 0; kx < 3; kx++) {
        int yy = py + ky - 1, xx = px + kx - 1;
        int tap = ky * 3 + kx;
        u64 m = 0;
        if (yy >= 0 && yy < 128 && xx >= 0 && xx < 128) {
          m = bin[yy * 128 + xx];
          vf |= 1 << tap; nvalid++;
        }
        nb[tap] = m;
      }
    bool interior = (vf == 511);
    int base = 64 * nvalid;

    u32 pk = 0;
#pragma unroll
    for (int jb = 0; jb < 16; jb += 4) {
#pragma unroll
      for (int s = 0; s < 4; s++) {
        int j = jb + s;
        int co = cg * 16 + j;
        int c = 0;
#pragma unroll
        for (int tap = 0; tap < 9; tap++)
          c += __popcll(nb[tap] ^ s_w[co * 9 + tap]);
        if (!interior) {
#pragma unroll
          for (int tap = 0; tap < 9; tap++)
            if (!((vf >> tap) & 1)) c -= __popcll(s_w[co * 9 + tap]);
        }
        int sint = base - 2 * c;
        float conv = fmul(s_sc[co], (float)sint);
        float t1 = fadd(conv, s_b1[co]);
        float t2 = t1 >= 0.0f ? t1 : fmul(s_a[co], t1);
        float t3 = fadd(t2, s_b2[co]);
        float ov = fadd(t3, res[j]);
        res[j] = ov;
        pk |= (u32)(fadd(ov, s_mv[co]) > 0.0f) << j;
      }
    }
    ((u16*)bout)[pix * 4 + cg] = (u16)pk;

    u64* tb = bin; bin = bout; bout = tb;
    if (u < 31) grid_barrier(bar, blk);
    // u=31 (odd) wrote bitsA; no barrier needed (kernel boundary orders it)
  }

  // ---- write final features for up1 --------------------------------------
  {
    float* An = A + (size_t)n * 1048576;
#pragma unroll
    for (int q = 0; q < 16; q++)
      An[(size_t)(cg * 16 + q) * 16384 + pix] = res[q];
  }
}

// --- binary conv + rprelu + residual (tail layers) -------------------------
// Block: 256 thr = 16x4 pixel tile x 4 co-groups (one wave per co-group).
// V_NHWC: write (pix,64) layout with leaky pre-applied (for conv_last).
template <int H, int W, int COUT, bool UPSHUF, bool PACK, bool V_NHWC>
__global__ __launch_bounds__(256) void bconv_kernel(
    const u64* __restrict__ bits_in,   // (H*W) packed acts
    const float* __restrict__ feat,    // (64,H,W) residual source
    const u64* __restrict__ wbits,     // (COUT,9)
    const float* __restrict__ scale, const float* __restrict__ pa,
    const float* __restrict__ pb1, const float* __restrict__ pb2,
    const float* __restrict__ nmove,   // (64) next layer's move
    float* __restrict__ out,           // see flags
    u64* __restrict__ bits_out)
{
  constexpr int NCO = COUT / 4;
  constexpr size_t HW = (size_t)H * W;
  __shared__ u64 s_w[COUT * 9];
  __shared__ float s_sc[COUT], s_a[COUT], s_b1[COUT], s_b2[COUT], s_mv[64];

  int t = threadIdx.x;
  for (int i = t; i < COUT * 9; i += 256) s_w[i] = wbits[i];
  for (int i = t; i < COUT; i += 256) {
    s_sc[i] = scale[i]; s_a[i] = pa[i]; s_b1[i] = pb1[i]; s_b2[i] = pb2[i];
  }
  if constexpr (PACK) {
    if (t < 64) s_mv[t] = nmove[t];
  }
  __syncthreads();

  int px = blockIdx.x * 16 + (t & 15);
  int py = blockIdx.y * 4 + ((t >> 4) & 3);
  int cg = t >> 6;
  int pix = py * W + px;

  u64 nb[9];
  int vf = 0, nvalid = 0;
#pragma unroll
  for (int ky = 0; ky < 3; ky++)
#pragma unroll
    for (int kx = 0; kx < 3; kx++) {
      int yy = py + ky - 1, xx = px + kx - 1;
      int tap = ky * 3 + kx;
      u64 m = 0;
      if (yy >= 0 && yy < H && xx >= 0 && xx < W) {
        m = bits_in[(size_t)yy * W + xx];
        vf |= 1 << tap; nvalid++;
      }
      nb[tap] = m;
    }
  bool interior = (vf == 511);
  int base = 64 * nvalid;

  u32 pk[UPSHUF ? 4 : 1];
#pragma unroll
  for (int s = 0; s < (UPSHUF ? 4 : 1); s++) pk[s] = 0;

  for (int jb = 0; jb < NCO; jb += 4) {
    float vq[4];
#pragma unroll
    for (int s = 0; s < 4; s++) {
      int j = jb + s;
      int co = cg * NCO + j;
      int c = 0;
#pragma unroll
      for (int tap = 0; tap < 9; tap++)
        c += __popcll(nb[tap] ^ s_w[co * 9 + tap]);
      if (!interior) {
#pragma unroll
        for (int tap = 0; tap < 9; tap++)
          if (!((vf >> tap) & 1)) c -= __popcll(s_w[co * 9 + tap]);
      }
      int sint = base - 2 * c;
      float conv = fmul(s_sc[co], (float)sint);
      float t1 = fadd(conv, s_b1[co]);
      float t2 = t1 >= 0.0f ? t1 : fmul(s_a[co], t1);
      float t3 = fadd(t2, s_b2[co]);
      if (!UPSHUF) {
        size_t fi = (size_t)co * HW + pix;
        float ov = fadd(t3, feat[fi]);
        if constexpr (V_NHWC) {
          vq[s] = ov >= 0.0f ? ov : fmul(0.1f, ov);   // leaky pre-applied
        } else {
          out[fi] = ov;
          if constexpr (PACK)
            pk[0] |= (u32)(fadd(ov, s_mv[co]) > 0.0f) << j;
        }
      } else {
        float ov = fadd(t3, feat[(size_t)j * HW + pix]);
        int oc = co >> 2;
        int dr = (j >> 1) & 1, dc = j & 1;
        size_t oi = ((size_t)oc * (2 * H) + (size_t)(2 * py + dr)) * (2 * W)
                    + (2 * px + dc);
        out[oi] = ov;
        if constexpr (PACK)
          pk[s] |= (u32)(fadd(ov, s_mv[oc]) > 0.0f) << (j >> 2);
      }
    }
    if constexpr (V_NHWC) {
      float4 v4 = make_float4(vq[0], vq[1], vq[2], vq[3]);
      *(float4*)(out + (size_t)pix * 64 + cg * NCO + jb) = v4;
    }
  }

  if constexpr (PACK) {
    if (!UPSHUF) {
      ((u16*)bits_out)[pix * 4 + cg] = (u16)pk[0];
    } else {
#pragma unroll
      for (int s = 0; s < 4; s++) {
        int dr = s >> 1, dc = s & 1;
        size_t opix = (size_t)(2 * py + dr) * (2 * W) + (2 * px + dc);
        ((u16*)bits_out)[opix * 4 + cg] = (u16)pk[s];
      }
    }
  }
}

// --- conv_last: V is NHWC (512*512, 64) with leaky pre-applied -------------
__global__ __launch_bounds__(256) void conv_last_kernel(
    const float* __restrict__ V,      // (512*512,64) leaky-applied
    const float* __restrict__ w, const float* __restrict__ b,
    const float* __restrict__ x,      // (3,128,128)
    float* __restrict__ out) {        // (3,512,512)
  int t = threadIdx.x;
  int gx = blockIdx.x * 16 + (t & 15);
  int gy = blockIdx.y * 16 + (t >> 4);
  float acc0 = 0.f, acc1 = 0.f, acc2 = 0.f;
  for (int ky = 0; ky < 3; ky++) {             // (ky,kx,ci), ci fastest
    int yy = gy + ky - 1;
    if (yy < 0 || yy > 511) continue;
    for (int kx = 0; kx < 3; kx++) {
      int xx = gx + kx - 1;
      if (xx < 0 || xx > 511) continue;
      int tap = ky * 3 + kx;
      const float4* vp = (const float4*)(V + ((size_t)(yy << 9) + xx) * 64);
#pragma unroll 4
      for (int c4 = 0; c4 < 16; c4++) {
        float4 v = vp[c4];
        int k = (c4 * 4) * 9 + tap;
        acc0 = fmaf(v.x, w[k], acc0);
        acc1 = fmaf(v.x, w[576 + k], acc1);
        acc2 = fmaf(v.x, w[1152 + k], acc2);
        acc0 = fmaf(v.y, w[k + 9], acc0);
        acc1 = fmaf(v.y, w[576 + k + 9], acc1);
        acc2 = fmaf(v.y, w[1152 + k + 9], acc2);
        acc0 = fmaf(v.z, w[k + 18], acc0);
        acc1 = fmaf(v.z, w[576 + k + 18], acc1);
        acc2 = fmaf(v.z, w[1152 + k + 18], acc2);
        acc0 = fmaf(v.w, w[k + 27], acc0);
        acc1 = fmaf(v.w, w[576 + k + 27], acc1);
        acc2 = fmaf(v.w, w[1152 + k + 27], acc2);
      }
    }
  }
  float o0 = fadd(acc0, b[0]);
  float o1 = fadd(acc1, b[1]);
  float o2 = fadd(acc2, b[2]);
  float sy = (gy + 0.5f) * 0.25f - 0.5f;
  float sx = (gx + 0.5f) * 0.25f - 0.5f;
  int iy0 = (int)floorf(sy);
  int ix0 = (int)floorf(sx);
  float fy = sy - (float)iy0, fx = sx - (float)ix0;
  int y0c = min(max(iy0, 0), 127), y1c = min(max(iy0 + 1, 0), 127);
  int x0c = min(max(ix0, 0), 127), x1c = min(max(ix0 + 1, 0), 127);
  float accs[3] = {o0, o1, o2};
#pragma unroll
  for (int co = 0; co < 3; co++) {
    const float* xp = x + (size_t)co * 16384;
    float c00 = xp[y0c * 128 + x0c], c01 = xp[y0c * 128 + x1c];
    float c10 = xp[y1c * 128 + x0c], c11 = xp[y1c * 128 + x1c];
    float v0, v1;
    if (y1c == y0c) { v0 = fmul(1.f, c00); v1 = fmul(1.f, c01); }
    else {
      v0 = fadd(fmul(1.f - fy, c00), fmul(fy, c10));
      v1 = fadd(fmul(1.f - fy, c01), fmul(fy, c11));
    }
    float base = (x1c == x0c) ? fmul(1.f, v0)
                              : fadd(fmul(1.f - fx, v0), fmul(fx, v1));
    out[((size_t)co << 18) + ((size_t)gy << 9) + gx] = fadd(accs[co], base);
  }
}

extern "C" void kernel_launch(void* const* d_in, const int* in_sizes, int n_in,
                              void* d_out, int out_size, void* d_ws,
                              size_t ws_size, hipStream_t stream) {
  const float* x         = (const float*)d_in[0];
  const float* cf_w      = (const float*)d_in[1];
  const float* cf_b      = (const float*)d_in[2];
  const float* body_move = (const float*)d_in[3];
  const float* body_w    = (const float*)d_in[4];
  const float* body_a    = (const float*)d_in[5];
  const float* body_b1   = (const float*)d_in[6];
  const float* body_b2   = (const float*)d_in[7];
  const float* up1_move  = (const float*)d_in[8];
  const float* up1_w     = (const float*)d_in[9];
  const float* up1_a     = (const float*)d_in[10];
  const float* up1_b1    = (const float*)d_in[11];
  const float* up1_b2    = (const float*)d_in[12];
  const float* up2_move  = (const float*)d_in[13];
  const float* up2_w     = (const float*)d_in[14];
  const float* up2_a     = (const float*)d_in[15];
  const float* up2_b1    = (const float*)d_in[16];
  const float* up2_b2    = (const float*)d_in[17];
  const float* hr_move   = (const float*)d_in[18];
  const float* hr_w      = (const float*)d_in[19];
  const float* hr_a      = (const float*)d_in[20];
  const float* hr_b1     = (const float*)d_in[21];
  const float* hr_b2     = (const float*)d_in[22];
  const float* cl_w      = (const float*)d_in[23];
  const float* cl_b      = (const float*)d_in[24];
  float* out = (float*)d_out;

  const size_t M = 1024 * 1024;
  if (ws_size < 160 * M) {
    diag_kernel<<<(out_size + 255) / 256, 256, 0, stream>>>(
        out, out_size, (float)(ws_size >> 20));
    return;
  }

  char* ws = (char*)d_ws;
  float* A    = (float*)(ws + 0);          // (4,64,128,128), 16M
  float* P    = (float*)(ws + 16 * M);     // (64,256,256) per-sample, 16M
  float* V    = (float*)(ws + 16 * M);     // (512*512,64) NHWC per-sample
                                           //   (aliases P after P consumed)
  float* U    = (float*)(ws + 80 * M);     // (64,512,512) per-sample, 64M
  u64* bitsA   = (u64*)(ws + 144 * M);     // (4,16384) 512K
  u64* bitsB   = (u64*)(ws + 144 * M + 512 * 1024);
  u64* bits256 = (u64*)(ws + 145 * M);     // (256*256) per-sample 512K
  u64* bits512 = (u64*)(ws + 146 * M);     // (512*512) 2M
  u64* wbits   = (u64*)(ws + 149 * M);     // 2624*9 u64
  float* scales = (float*)(ws + 150 * M);  // 2624 f32
  u32* bar     = (u32*)(ws + 151 * M);     // barrier state, 521 u32

  // zero barrier state (stream-ordered; capture-legal async op)
  hipMemsetAsync(bar, 0, 2176, stream);

  // weight prep
  binw_pack_kernel<<<32, 64, 0, stream>>>(body_w, wbits, scales, 2048);
  binw_pack_kernel<<<4, 64, 0, stream>>>(up1_w, wbits + (size_t)2048 * 9,
                                         scales + 2048, 256);
  binw_pack_kernel<<<4, 64, 0, stream>>>(up2_w, wbits + (size_t)2304 * 9,
                                         scales + 2304, 256);
  binw_pack_kernel<<<1, 64, 0, stream>>>(hr_w, wbits + (size_t)2560 * 9,
                                         scales + 2560, 64);

  // fused head + 32 body layers (persistent; hand-rolled grid barrier)
  fused_body_kernel<<<dim3(NBLK), 256, 0, stream>>>(
      x, cf_w, cf_b, body_move, body_a, body_b1, body_b2, up1_move,
      A, bitsA, bitsB, wbits, scales, bar);
  // body out in A, its bits (packed w/ up1_move) in bitsA

  // per sample: up1 -> up2 -> hr -> conv_last
  for (int n = 0; n < 4; n++) {
    // up1: (64,128,128) -> (64,256,256) in P; packs bits with up2_move
    bconv_kernel<128, 128, 256, true, true, false>
        <<<dim3(8, 32, 1), 256, 0, stream>>>(
            bitsA + (size_t)n * 16384, A + (size_t)n * 1048576,
            wbits + (size_t)2048 * 9, scales + 2048,
            up1_a, up1_b1, up1_b2, up2_move, P, bits256);
    // up2: (64,256,256) -> (64,512,512) in U; packs bits with hr_move
    bconv_kernel<256, 256, 256, true, true, false>
        <<<dim3(16, 64, 1), 256, 0, stream>>>(
            bits256, P, wbits + (size_t)2304 * 9, scales + 2304,
            up2_a, up2_b1, up2_b2, hr_move, U, bits512);
    // hr: (64,512,512) -> V NHWC with leaky pre-applied (P dead; V aliases)
    bconv_kernel<512, 512, 64, false, false, true>
        <<<dim3(32, 128, 1), 256, 0, stream>>>(
            bits512, U, wbits + (size_t)2560 * 9, scales + 2560,
            hr_a, hr_b1, hr_b2, hr_move, V, nullptr);
    // conv_last + bilinear base (16x16 tiles, float4 NHWC reads)
    conv_last_kernel<<<dim3(32, 32), 256, 0, stream>>>(
        V, cl_w, cl_b, x + (size_t)n * 49152,
        out + (size_t)n * 3 * 262144);
  }
}